// Round 9
// baseline (151.843 us; speedup 1.0000x reference)
//
#include <hip/hip_runtime.h>
#include <hip/hip_bf16.h>

#define N_GROUPS 368
#define NMODELS  64
#define BATCH    4096
#define RPB      32    // batch rows per block
#define GPB      8     // groups per block (one per wave)

typedef __attribute__((ext_vector_type(8)))  short short8v;  // 8 bf16 (4 VGPRs)
typedef __attribute__((ext_vector_type(16))) float f32x16;   // 32x32 MFMA acc

// split fp32 into bf16 hi + bf16 lo (residual)
__device__ inline void bf_split(float v, unsigned short& hi, unsigned short& lo) {
    const __hip_bfloat16 h = __float2bfloat16(v);
    const float r = v - __bfloat162float(h);
    const __hip_bfloat16 l = __float2bfloat16(r);
    hi = __builtin_bit_cast(unsigned short, h);
    lo = __builtin_bit_cast(unsigned short, l);
}

__device__ inline float bf2f(short u) {
    return __builtin_bit_cast(float, ((unsigned)(unsigned short)u) << 16);
}

// split 8 fp32 (two float4) into hi/lo short8v fragments
__device__ inline void split8(const float4 a, const float4 b, short8v& h, short8v& l) {
    unsigned short hh, ll;
    bf_split(a.x, hh, ll); h[0] = (short)hh; l[0] = (short)ll;
    bf_split(a.y, hh, ll); h[1] = (short)hh; l[1] = (short)ll;
    bf_split(a.z, hh, ll); h[2] = (short)hh; l[2] = (short)ll;
    bf_split(a.w, hh, ll); h[3] = (short)hh; l[3] = (short)ll;
    bf_split(b.x, hh, ll); h[4] = (short)hh; l[4] = (short)ll;
    bf_split(b.y, hh, ll); h[5] = (short)hh; l[5] = (short)ll;
    bf_split(b.z, hh, ll); h[6] = (short)hh; l[6] = (short)ll;
    bf_split(b.w, hh, ll); h[7] = (short)hh; l[7] = (short)ll;
}

// XOR swizzle on row-relative SHORT offset (flips 16B..64B slot bits).
// Same involution on write and read.
#define SWZ(row, soff) ((soff) ^ (((row) & 7) << 3))

__global__ __launch_bounds__(512, 4) void ensemble_mg(
    const float* __restrict__ x,     // [BATCH][N_GROUPS][NMODELS]
    const float* __restrict__ W,     // [N_GROUPS][NMODELS][NMODELS]
    const float* __restrict__ bias,  // [N_GROUPS][NMODELS]
    float* __restrict__ out)         // [BATCH][N_GROUPS]
{
    __shared__ __hip_bfloat16 Xh[GPB][RPB * 64];  // 8 x 4 KB
    __shared__ __hip_bfloat16 Xl[GPB][RPB * 64];  // 8 x 4 KB  -> 64 KB, 2 blocks/CU

    const int g0   = blockIdx.y * GPB;
    const int row0 = blockIdx.x * RPB;
    const int t    = threadIdx.x;

    const int lane = t & 63;
    const int wv   = t >> 6;      // wave id -> group g0+wv
    const int cl   = lane & 31;   // frag row (W-row m, X/batch row c)
    const int h2   = lane >> 5;   // k-group selector
    const int g    = g0 + wv;

    // ---- prefetch this wave's W[g] fragments (raw fp32) before the sync ----
    const float* __restrict__ Wg = W + (size_t)g * NMODELS * NMODELS;
    float4 wr[4][4];
    #pragma unroll
    for (int ks = 0; ks < 4; ++ks) {
        const int ko = ks * 16 + 8 * h2;
        wr[ks][0] = *reinterpret_cast<const float4*>(Wg + cl * 64 + ko);
        wr[ks][1] = *reinterpret_cast<const float4*>(Wg + cl * 64 + ko + 4);
        wr[ks][2] = *reinterpret_cast<const float4*>(Wg + (32 + cl) * 64 + ko);
        wr[ks][3] = *reinterpret_cast<const float4*>(Wg + (32 + cl) * 64 + ko + 4);
    }

    // ---- stage X: 32 rows x 8 groups x 64 fp32; 2 KB contiguous per row ----
    #pragma unroll
    for (int j = 0; j < 8; ++j) {
        const int r   = (t >> 7) + 4 * j;     // row within tile
        const int idx = (t & 127) * 4;        // float index within 2KB row-chunk
        const int gi  = idx >> 6;             // group within block
        const int n0  = idx & 63;             // feature index
        const float4 v = *reinterpret_cast<const float4*>(
            x + ((size_t)(row0 + r) * N_GROUPS + g0) * NMODELS + idx);
        unsigned short h_[4], l_[4];
        bf_split(v.x, h_[0], l_[0]); bf_split(v.y, h_[1], l_[1]);
        bf_split(v.z, h_[2], l_[2]); bf_split(v.w, h_[3], l_[3]);
        const int so = r * 64 + SWZ(r, n0);
        *reinterpret_cast<short4*>(&Xh[gi][so]) =
            make_short4((short)h_[0], (short)h_[1], (short)h_[2], (short)h_[3]);
        *reinterpret_cast<short4*>(&Xl[gi][so]) =
            make_short4((short)l_[0], (short)l_[1], (short)l_[2], (short)l_[3]);
    }
    __syncthreads();

    // ---- MFMA: Y^T = W[g] . X^T ; D col = batch row (lane&31), D row = m ----
    f32x16 acc0, acc1;
    #pragma unroll
    for (int r = 0; r < 16; ++r) { acc0[r] = 0.f; acc1[r] = 0.f; }

    #pragma unroll
    for (int ks = 0; ks < 4; ++ks) {
        const int ko = ks * 16 + 8 * h2;
        const int xo = cl * 64 + SWZ(cl, ko);
        const short8v bh = *reinterpret_cast<const short8v*>(&Xh[wv][xo]);
        const short8v bl = *reinterpret_cast<const short8v*>(&Xl[wv][xo]);

        short8v ah0, al0, ah1, al1;
        split8(wr[ks][0], wr[ks][1], ah0, al0);   // tile 0: m = cl
        split8(wr[ks][2], wr[ks][3], ah1, al1);   // tile 1: m = 32+cl

        acc0 = __builtin_amdgcn_mfma_f32_32x32x16_bf16(ah0, bh, acc0, 0, 0, 0);
        acc0 = __builtin_amdgcn_mfma_f32_32x32x16_bf16(ah0, bl, acc0, 0, 0, 0);
        acc0 = __builtin_amdgcn_mfma_f32_32x32x16_bf16(al0, bh, acc0, 0, 0, 0);

        acc1 = __builtin_amdgcn_mfma_f32_32x32x16_bf16(ah1, bh, acc1, 0, 0, 0);
        acc1 = __builtin_amdgcn_mfma_f32_32x32x16_bf16(ah1, bl, acc1, 0, 0, 0);
        acc1 = __builtin_amdgcn_mfma_f32_32x32x16_bf16(al1, bh, acc1, 0, 0, 0);
    }

    // ---- bias (after MFMA; 8 float4 loads) ----
    // lane's m-slots: m = tt*32 + 8*rq + 4*h2 + p ; acc reg r = 4*rq + p
    float4 bv4[2][4];
    #pragma unroll
    for (int tt = 0; tt < 2; ++tt)
        #pragma unroll
        for (int rq = 0; rq < 4; ++rq)
            bv4[tt][rq] = *reinterpret_cast<const float4*>(
                bias + (size_t)g * 64 + tt * 32 + 8 * rq + 4 * h2);

    // ---- epilogue: softmax over m (in-register) + dot with x ----
    float y[2][16];
    #pragma unroll
    for (int tt = 0; tt < 2; ++tt)
        #pragma unroll
        for (int rq = 0; rq < 4; ++rq) {
            const f32x16& a = tt ? acc1 : acc0;
            y[tt][4*rq+0] = a[4*rq+0] + bv4[tt][rq].x;
            y[tt][4*rq+1] = a[4*rq+1] + bv4[tt][rq].y;
            y[tt][4*rq+2] = a[4*rq+2] + bv4[tt][rq].z;
            y[tt][4*rq+3] = a[4*rq+3] + bv4[tt][rq].w;
        }

    float mx = y[0][0];
    #pragma unroll
    for (int r = 1; r < 16; ++r) mx = fmaxf(mx, y[0][r]);
    #pragma unroll
    for (int r = 0; r < 16; ++r) mx = fmaxf(mx, y[1][r]);
    mx = fmaxf(mx, __shfl_xor(mx, 32));

    float S = 0.f, P = 0.f;
    #pragma unroll
    for (int tt = 0; tt < 2; ++tt)
        #pragma unroll
        for (int j = 0; j < 4; ++j) {
            // x[cl][m] for m-group tt*32 + 8j + 4*h2 .. +3
            const int so = cl * 64 + SWZ(cl, tt * 32 + 8 * j + 4 * h2);
            const short4 vh = *reinterpret_cast<const short4*>(&Xh[wv][so]);
            const short4 vl = *reinterpret_cast<const short4*>(&Xl[wv][so]);
            const float xv0 = bf2f(vh.x) + bf2f(vl.x);
            const float xv1 = bf2f(vh.y) + bf2f(vl.y);
            const float xv2 = bf2f(vh.z) + bf2f(vl.z);
            const float xv3 = bf2f(vh.w) + bf2f(vl.w);
            const float e0 = __expf(y[tt][4*j+0] - mx);
            const float e1 = __expf(y[tt][4*j+1] - mx);
            const float e2 = __expf(y[tt][4*j+2] - mx);
            const float e3 = __expf(y[tt][4*j+3] - mx);
            S += (e0 + e1) + (e2 + e3);
            P = __builtin_fmaf(e0, xv0, P);
            P = __builtin_fmaf(e1, xv1, P);
            P = __builtin_fmaf(e2, xv2, P);
            P = __builtin_fmaf(e3, xv3, P);
        }
    S += __shfl_xor(S, 32);
    P += __shfl_xor(P, 32);

    if (h2 == 0)
        out[(size_t)(row0 + cl) * N_GROUPS + g] = P / S;
}

extern "C" void kernel_launch(void* const* d_in, const int* in_sizes, int n_in,
                              void* d_out, int out_size, void* d_ws, size_t ws_size,
                              hipStream_t stream) {
    const float* x  = (const float*)d_in[0];
    const float* W  = (const float*)d_in[1];
    const float* b  = (const float*)d_in[2];
    float* out = (float*)d_out;

    dim3 grid(BATCH / RPB, N_GROUPS / GPB);   // (128, 46)
    dim3 block(512);
    ensemble_mg<<<grid, block, 0, stream>>>(x, W, b, out);
}

// Round 10
// 118.502 us; speedup vs baseline: 1.2813x; 1.2813x over previous
//
#include <hip/hip_runtime.h>
#include <hip/hip_bf16.h>
#include <stdint.h>

#define N_GROUPS 368
#define NMODELS  64
#define BATCH    4096
#define ROWS     256   // batch rows per block (8 waves x 32)

typedef __attribute__((ext_vector_type(8)))  short short8v;  // 8 bf16 (4 VGPRs)
typedef __attribute__((ext_vector_type(16))) float f32x16;   // 32x32 MFMA acc

__device__ inline uint32_t f2u(float f) { return __builtin_bit_cast(uint32_t, f); }
__device__ inline float    u2f(uint32_t u) { return __builtin_bit_cast(float, u); }
__device__ inline float    bf2f(short s) { return u2f(((uint32_t)(unsigned short)s) << 16); }

// cheap split: hi = round-half-up bf16 (1 add + 1 and), lo = trunc bf16 of residual.
// residual error ~2^-17 rel; packs two bf16 per u32 (low short = first element).
__device__ inline void split4(const float4 v, uint2& hp, uint2& lp) {
    const uint32_t hx = (f2u(v.x) + 0x8000u) & 0xFFFF0000u;
    const uint32_t hy = (f2u(v.y) + 0x8000u) & 0xFFFF0000u;
    const uint32_t hz = (f2u(v.z) + 0x8000u) & 0xFFFF0000u;
    const uint32_t hw = (f2u(v.w) + 0x8000u) & 0xFFFF0000u;
    hp.x = (hx >> 16) | hy;
    hp.y = (hz >> 16) | hw;
    lp.x = (f2u(v.x - u2f(hx)) >> 16) | (f2u(v.y - u2f(hy)) & 0xFFFF0000u);
    lp.y = (f2u(v.z - u2f(hz)) >> 16) | (f2u(v.w - u2f(hw)) & 0xFFFF0000u);
}

// XOR swizzle on row-relative SHORT offset (flips 16B..64B slot bits).
// Same involution on write and read.
#define SWZ(row, soff) ((soff) ^ (((row) & 7) << 3))

__global__ __launch_bounds__(512, 4) void ensemble_pipe(
    const float* __restrict__ x,     // [BATCH][N_GROUPS][NMODELS]
    const float* __restrict__ W,     // [N_GROUPS][NMODELS][NMODELS]
    const float* __restrict__ bias,  // [N_GROUPS][NMODELS]
    float* __restrict__ out)         // [BATCH][N_GROUPS]
{
    __shared__ __hip_bfloat16 Xh[ROWS * 64];  // 32 KB
    __shared__ __hip_bfloat16 Xl[ROWS * 64];  // 32 KB
    __shared__ __hip_bfloat16 Wh[64 * 64];    //  8 KB
    __shared__ __hip_bfloat16 Wl[64 * 64];    //  8 KB  -> 80 KB, 2 blocks/CU

    const int g    = blockIdx.y;
    const int row0 = blockIdx.x * ROWS;
    const int t    = threadIdx.x;

    // staging maps: 2 threads per row, 16 floats each per k-half
    const int sr = t >> 1;            // row 0..255
    const int f0 = (t & 1) * 16;      // feature base within k-half
    const float* __restrict__ xrow =
        x + ((size_t)(row0 + sr) * N_GROUPS + g) * NMODELS;

    const int wm = t >> 3;            // W row 0..63
    const int wc = (t & 7) * 8;       // W col base (8 floats)
    const float* __restrict__ Wgp =
        W + (size_t)g * NMODELS * NMODELS + (size_t)wm * NMODELS + wc;

    // (1) issue k-half-0 x loads + W loads
    float4 q0[4];
    #pragma unroll
    for (int j = 0; j < 4; ++j)
        q0[j] = *reinterpret_cast<const float4*>(xrow + f0 + 4 * j);
    float4 wq[2];
    #pragma unroll
    for (int j = 0; j < 2; ++j)
        wq[j] = *reinterpret_cast<const float4*>(Wgp + 4 * j);

    // (2) split + write k0 & W to LDS
    #pragma unroll
    for (int j = 0; j < 4; ++j) {
        uint2 hp, lp; split4(q0[j], hp, lp);
        const int so = sr * 64 + SWZ(sr, f0 + 4 * j);
        *reinterpret_cast<uint2*>(&Xh[so]) = hp;
        *reinterpret_cast<uint2*>(&Xl[so]) = lp;
    }
    #pragma unroll
    for (int j = 0; j < 2; ++j) {
        uint2 hp, lp; split4(wq[j], hp, lp);
        const int so = wm * 64 + SWZ(wm, wc + 4 * j);
        *reinterpret_cast<uint2*>(&Wh[so]) = hp;
        *reinterpret_cast<uint2*>(&Wl[so]) = lp;
    }
    __syncthreads();

    // (3) issue k-half-1 x loads NOW; latency hides under MFMA phase 0
    float4 q1[4];
    #pragma unroll
    for (int j = 0; j < 4; ++j)
        q1[j] = *reinterpret_cast<const float4*>(xrow + 32 + f0 + 4 * j);

    const int lane = t & 63;
    const int wv   = t >> 6;      // wave id -> batch-row tile
    const int cl   = lane & 31;
    const int h2   = lane >> 5;
    const int c    = wv * 32 + cl;   // this lane's batch row

    f32x16 acc0, acc1;
    #pragma unroll
    for (int r = 0; r < 16; ++r) { acc0[r] = 0.f; acc1[r] = 0.f; }

    // (4) MFMA phase 0: ks = 0,1 (features 0..31)
    #pragma unroll
    for (int ks = 0; ks < 2; ++ks) {
        const int ko = ks * 16 + 8 * h2;
        const int xo = c * 64 + SWZ(c, ko);
        const short8v bh = *reinterpret_cast<const short8v*>(&Xh[xo]);
        const short8v bl = *reinterpret_cast<const short8v*>(&Xl[xo]);

        const int wo0 = cl * 64 + SWZ(cl, ko);
        const short8v ah0 = *reinterpret_cast<const short8v*>(&Wh[wo0]);
        const short8v al0 = *reinterpret_cast<const short8v*>(&Wl[wo0]);
        acc0 = __builtin_amdgcn_mfma_f32_32x32x16_bf16(ah0, bh, acc0, 0, 0, 0);
        acc0 = __builtin_amdgcn_mfma_f32_32x32x16_bf16(ah0, bl, acc0, 0, 0, 0);
        acc0 = __builtin_amdgcn_mfma_f32_32x32x16_bf16(al0, bh, acc0, 0, 0, 0);

        const int m1  = 32 + cl;
        const int wo1 = m1 * 64 + SWZ(m1, ko);
        const short8v ah1 = *reinterpret_cast<const short8v*>(&Wh[wo1]);
        const short8v al1 = *reinterpret_cast<const short8v*>(&Wl[wo1]);
        acc1 = __builtin_amdgcn_mfma_f32_32x32x16_bf16(ah1, bh, acc1, 0, 0, 0);
        acc1 = __builtin_amdgcn_mfma_f32_32x32x16_bf16(ah1, bl, acc1, 0, 0, 0);
        acc1 = __builtin_amdgcn_mfma_f32_32x32x16_bf16(al1, bh, acc1, 0, 0, 0);
    }

    // (5) split + write k1 (vmcnt lands here, after phase-0 compute); barrier.
    //     No hazard: phase-0 reads features 0..31, these writes touch 32..63.
    #pragma unroll
    for (int j = 0; j < 4; ++j) {
        uint2 hp, lp; split4(q1[j], hp, lp);
        const int so = sr * 64 + SWZ(sr, 32 + f0 + 4 * j);
        *reinterpret_cast<uint2*>(&Xh[so]) = hp;
        *reinterpret_cast<uint2*>(&Xl[so]) = lp;
    }
    __syncthreads();

    // (6) MFMA phase 1: ks = 2,3 (features 32..63)
    #pragma unroll
    for (int ks = 2; ks < 4; ++ks) {
        const int ko = ks * 16 + 8 * h2;
        const int xo = c * 64 + SWZ(c, ko);
        const short8v bh = *reinterpret_cast<const short8v*>(&Xh[xo]);
        const short8v bl = *reinterpret_cast<const short8v*>(&Xl[xo]);

        const int wo0 = cl * 64 + SWZ(cl, ko);
        const short8v ah0 = *reinterpret_cast<const short8v*>(&Wh[wo0]);
        const short8v al0 = *reinterpret_cast<const short8v*>(&Wl[wo0]);
        acc0 = __builtin_amdgcn_mfma_f32_32x32x16_bf16(ah0, bh, acc0, 0, 0, 0);
        acc0 = __builtin_amdgcn_mfma_f32_32x32x16_bf16(ah0, bl, acc0, 0, 0, 0);
        acc0 = __builtin_amdgcn_mfma_f32_32x32x16_bf16(al0, bh, acc0, 0, 0, 0);

        const int m1  = 32 + cl;
        const int wo1 = m1 * 64 + SWZ(m1, ko);
        const short8v ah1 = *reinterpret_cast<const short8v*>(&Wh[wo1]);
        const short8v al1 = *reinterpret_cast<const short8v*>(&Wl[wo1]);
        acc1 = __builtin_amdgcn_mfma_f32_32x32x16_bf16(ah1, bh, acc1, 0, 0, 0);
        acc1 = __builtin_amdgcn_mfma_f32_32x32x16_bf16(ah1, bl, acc1, 0, 0, 0);
        acc1 = __builtin_amdgcn_mfma_f32_32x32x16_bf16(al1, bh, acc1, 0, 0, 0);
    }

    // (7) bias (after MFMA; 8 float4 loads)
    // lane's m-slots: m = tt*32 + 8*rq + 4*h2 + p ; acc reg r = 4*rq + p
    float4 bv4[2][4];
    #pragma unroll
    for (int tt = 0; tt < 2; ++tt)
        #pragma unroll
        for (int rq = 0; rq < 4; ++rq)
            bv4[tt][rq] = *reinterpret_cast<const float4*>(
                bias + (size_t)g * 64 + tt * 32 + 8 * rq + 4 * h2);

    // (8) epilogue: softmax over m (in-register) + dot with x
    float y[2][16];
    #pragma unroll
    for (int tt = 0; tt < 2; ++tt)
        #pragma unroll
        for (int rq = 0; rq < 4; ++rq) {
            const f32x16& a = tt ? acc1 : acc0;
            y[tt][4*rq+0] = a[4*rq+0] + bv4[tt][rq].x;
            y[tt][4*rq+1] = a[4*rq+1] + bv4[tt][rq].y;
            y[tt][4*rq+2] = a[4*rq+2] + bv4[tt][rq].z;
            y[tt][4*rq+3] = a[4*rq+3] + bv4[tt][rq].w;
        }

    float mx = y[0][0];
    #pragma unroll
    for (int r = 1; r < 16; ++r) mx = fmaxf(mx, y[0][r]);
    #pragma unroll
    for (int r = 0; r < 16; ++r) mx = fmaxf(mx, y[1][r]);
    mx = fmaxf(mx, __shfl_xor(mx, 32));

    float S = 0.f, P = 0.f;
    #pragma unroll
    for (int tt = 0; tt < 2; ++tt)
        #pragma unroll
        for (int j = 0; j < 4; ++j) {
            const int so = c * 64 + SWZ(c, tt * 32 + 8 * j + 4 * h2);
            const short4 vh = *reinterpret_cast<const short4*>(&Xh[so]);
            const short4 vl = *reinterpret_cast<const short4*>(&Xl[so]);
            const float xv0 = bf2f(vh.x) + bf2f(vl.x);
            const float xv1 = bf2f(vh.y) + bf2f(vl.y);
            const float xv2 = bf2f(vh.z) + bf2f(vl.z);
            const float xv3 = bf2f(vh.w) + bf2f(vl.w);
            const float e0 = __expf(y[tt][4*j+0] - mx);
            const float e1 = __expf(y[tt][4*j+1] - mx);
            const float e2 = __expf(y[tt][4*j+2] - mx);
            const float e3 = __expf(y[tt][4*j+3] - mx);
            S += (e0 + e1) + (e2 + e3);
            P = __builtin_fmaf(e0, xv0, P);
            P = __builtin_fmaf(e1, xv1, P);
            P = __builtin_fmaf(e2, xv2, P);
            P = __builtin_fmaf(e3, xv3, P);
        }
    S += __shfl_xor(S, 32);
    P += __shfl_xor(P, 32);

    if (h2 == 0)
        out[(size_t)(row0 + c) * N_GROUPS + g] = P / S;
}

extern "C" void kernel_launch(void* const* d_in, const int* in_sizes, int n_in,
                              void* d_out, int out_size, void* d_ws, size_t ws_size,
                              hipStream_t stream) {
    const float* x  = (const float*)d_in[0];
    const float* W  = (const float*)d_in[1];
    const float* b  = (const float*)d_in[2];
    float* out = (float*)d_out;

    dim3 grid(BATCH / ROWS, N_GROUPS);   // (16, 368)
    dim3 block(512);
    ensemble_pipe<<<grid, block, 0, stream>>>(x, W, b, out);
}